// Round 4
// baseline (338.934 us; speedup 1.0000x reference)
//
#include <hip/hip_runtime.h>

// DCGRU cell, MI355X.
//   Diffusion intermediates TRANSPOSED: XT[col = f*64+b][node n] in bf16.
//   Chebyshev recursion FOLDED: T_z = 2*S_z^2 - I precomputed (sq_gemm), so
//   each gconv is ONE launch: [S0;T0;S1;T1](4096x1024) @ X(1024x4224).
//   gconv_gemm/sq_gemm core: 256x128 tile, BK=32, THREE LDS buffers (72KB,
//     2 blocks/CU), depth-2 prefetch with counted vmcnt(6) (never 0 in main
//     loop). Per-step MFMA = 32/wave -> per-SIMD step ~620cyc -> depth-2
//     cover ~1240cyc > HBM-miss latency (per-XCD working set can't L2-fit,
//     so we out-cover L3/HBM latency instead). XOR swizzle via pre-swizzled
//     GLOBAL source (global_load_lds writes linearly). XCD-bijective grid.
//   proj1/proj2: A staged in LDS as [n][kp] row stride 360 (720B: 5n mod 8
//     bijective -> conflict-free ds_read_b128 A-frags, ONE per 32-k step).
//     B-frags straight from global Wt (L2-hot). d_out doubles as u-buffer.

typedef unsigned short u16;
typedef unsigned int u32;
typedef short s16x8 __attribute__((ext_vector_type(8)));
typedef float f32x4 __attribute__((ext_vector_type(4)));
typedef u16 u16x4 __attribute__((ext_vector_type(4)));

#define NN 1024
#define NB 64
#define NF 66
#define NCOLS 4224  // NF*NB
#define KPAD 352    // 330 padded to 11*32
#define ASTRIDE 360 // proj A-LDS row stride in u16 (720B, 5n%8 bijection)

__device__ __forceinline__ u16 f2bf(float f) {
  u32 u = __builtin_bit_cast(u32, f);
  u = (u + 0x7fffu + ((u >> 16) & 1u)) >> 16;  // RNE
  return (u16)u;
}
__device__ __forceinline__ float bf2f(u16 h) {
  u32 u = ((u32)h) << 16;
  return __builtin_bit_cast(float, u);
}

__device__ __forceinline__ void gload16(const void* g, void* l) {
  __builtin_amdgcn_global_load_lds(
      (const __attribute__((address_space(1))) u32*)g,
      (__attribute__((address_space(3))) u32*)l, 16, 0, 0);
}

// counted-vmcnt barrier: own oldest loads landed -> barrier -> fence reads
#define CHEB_WAIT(N)                                      \
  do {                                                    \
    asm volatile("s_waitcnt vmcnt(" #N ")" ::: "memory"); \
    __builtin_amdgcn_s_barrier();                         \
    asm volatile("" ::: "memory");                        \
  } while (0)

// ---------------- pack kernels ----------------

// 64x64 f32 tiles: write bf16 S_z into Acat S-rows (z*2048 base) and bf16
// transpose into ST_z (for sq_gemm's A operand).
__global__ __launch_bounds__(256) void pack_supports(
    const float* __restrict__ s0, const float* __restrict__ s1,
    u16* __restrict__ Acat, u16* __restrict__ ST0, u16* __restrict__ ST1) {
  __shared__ float tile[64][65];
  const int z = blockIdx.y;
  const float* S = z ? s1 : s0;
  u16* ST = z ? ST1 : ST0;
  const int r0 = (blockIdx.x >> 4) * 64, c0 = (blockIdx.x & 15) * 64;
  const int t = threadIdx.x;
  const size_t sbase = (size_t)z * 2048 * NN;
  int cc4 = (t & 15) * 4, rr = t >> 4;
#pragma unroll
  for (int p = 0; p < 4; p++) {
    int r = p * 16 + rr;
    f32x4 v = *(const f32x4*)(S + (size_t)(r0 + r) * NN + c0 + cc4);
    tile[r][cc4] = v.x; tile[r][cc4 + 1] = v.y;
    tile[r][cc4 + 2] = v.z; tile[r][cc4 + 3] = v.w;
    u16x4 o;
    o.x = f2bf(v.x); o.y = f2bf(v.y); o.z = f2bf(v.z); o.w = f2bf(v.w);
    *(u16x4*)&Acat[sbase + (size_t)(r0 + r) * NN + c0 + cc4] = o;
  }
  __syncthreads();
  int rr4 = (t & 15) * 4, cc = t >> 4;
#pragma unroll
  for (int p = 0; p < 4; p++) {
    int c = p * 16 + cc;
    u16x4 o;
    o.x = f2bf(tile[rr4][c]);     o.y = f2bf(tile[rr4 + 1][c]);
    o.z = f2bf(tile[rr4 + 2][c]); o.w = f2bf(tile[rr4 + 3][c]);
    *(u16x4*)&ST[(size_t)(c0 + c) * NN + r0 + rr4] = o;
  }
}

// Wt[o][kp] = W[f*5+m][o], kp = m*66+f, zero-padded kp in [330,352)
__global__ __launch_bounds__(64) void pack_w(
    const float* __restrict__ W, u16* __restrict__ Wt, int ldo) {
  int o = blockIdx.y;
  int kp = blockIdx.x * 64 + threadIdx.x;
  if (kp >= KPAD) return;
  float v = 0.f;
  if (kp < 330) {
    int m = kp / 66;
    int f = kp - m * 66;
    v = W[(f * 5 + m) * ldo + o];
  }
  Wt[(size_t)o * KPAD + kp] = f2bf(v);
}

// rows f=0,1 of X0^T and X0'^T: X0T[f*64+b][n] = inputs[b][2n+f]
__global__ __launch_bounds__(256) void pack_x0_inputs(
    const float* __restrict__ inp, u16* __restrict__ x0t, u16* __restrict__ x0pt) {
  int b = blockIdx.x, t = threadIdx.x;
  int n4 = t * 4;
  const float* src = inp + b * 2048 + n4 * 2;
  f32x4 a = *(const f32x4*)src;
  f32x4 c = *(const f32x4*)(src + 4);
  u16x4 r0, r1;
  r0.x = f2bf(a.x); r0.y = f2bf(a.z); r0.z = f2bf(c.x); r0.w = f2bf(c.z);  // f=0
  r1.x = f2bf(a.y); r1.y = f2bf(a.w); r1.z = f2bf(c.y); r1.w = f2bf(c.w);  // f=1
  size_t o0 = (size_t)(b)*NN + n4;
  size_t o1 = (size_t)(64 + b) * NN + n4;
  *(u16x4*)(x0t + o0) = r0;  *(u16x4*)(x0t + o1) = r1;
  *(u16x4*)(x0pt + o0) = r0; *(u16x4*)(x0pt + o1) = r1;
}

// rows f>=2 of X0^T: X0T[(2+u)*64+b][n] = hx[b][n*64+u]  (64x64 LDS transpose tiles)
__global__ __launch_bounds__(256) void pack_x0_hx(
    const float* __restrict__ hx, u16* __restrict__ x0t) {
  __shared__ float tile[64][65];
  int n0 = blockIdx.x * 64, b = blockIdx.y, t = threadIdx.x;
  int u4 = (t & 15) * 4, r0 = t >> 4;
#pragma unroll
  for (int p = 0; p < 4; p++) {
    int row = p * 16 + r0;
    f32x4 v = *(const f32x4*)(hx + ((size_t)b << 16) + (size_t)(n0 + row) * 64 + u4);
    tile[row][u4] = v.x; tile[row][u4 + 1] = v.y;
    tile[row][u4 + 2] = v.z; tile[row][u4 + 3] = v.w;
  }
  __syncthreads();
  int n4 = (t & 15) * 4, uu0 = t >> 4;
#pragma unroll
  for (int p = 0; p < 4; p++) {
    int u = p * 16 + uu0;
    u16x4 o;
    o.x = f2bf(tile[n4][u]);     o.y = f2bf(tile[n4 + 1][u]);
    o.z = f2bf(tile[n4 + 2][u]); o.w = f2bf(tile[n4 + 3][u]);
    *(u16x4*)&x0t[(size_t)((2 + u) * 64 + b) * NN + n0 + n4] = o;
  }
}

// ---------------- pipelined 256x128xK=1024 GEMM core ----------------
// A,B row-major-over-K bf16, K=1024, BK=32, 3 LDS buffers, depth-2 prefetch.
// LDS row = 4 chunks of 16B; logical chunk c of row r at physical c^((r>>1)&3)
// (pre-swizzled global source; global_load_lds writes linearly).
// Wave w: stages A rows [w*64,w*64+64) (4 gloads) + B rows [w*32,w*32+32)
// (2 gloads); computes C quadrant [ (w>>1)*128 x (w&1)*64 ] as acc[8][4].

__device__ __forceinline__ void gemm256_pipe(
    const u16* pA, const u16* pB,  // per-lane global src (row & swizzle applied)
    u16* As, u16* Bs,              // 3 buffers: 256*32 / 128*32 u16 each
    int w, int lane, f32x4 acc[8][4]) {
  const int dbA = (w * 64) * 32;   // wave-uniform LDS dest (u16)
  const int dbB = (w * 32) * 32;
  const u16* a0 = pA;
  const u16* b0 = pB;
  const int wm = (w >> 1) * 128;
  const int wn = (w & 1) * 64;
  const int fr = lane & 15;
  const int q = lane >> 4;
  const int fo = (q ^ ((fr >> 1) & 3)) * 8;  // frag chunk un-swizzle

  auto stage = [&](int buf) {
    u16* dA = As + buf * (256 * 32);
    u16* dB = Bs + buf * (128 * 32);
    gload16(a0, dA + dbA);
    gload16(a0 + (size_t)16 * NN, dA + dbA + 16 * 32);
    gload16(a0 + (size_t)32 * NN, dA + dbA + 32 * 32);
    gload16(a0 + (size_t)48 * NN, dA + dbA + 48 * 32);
    gload16(b0, dB + dbB);
    gload16(b0 + (size_t)16 * NN, dB + dbB + 16 * 32);
    a0 += 32; b0 += 32;
  };
  auto compute = [&](int buf) {
    const u16* cA = As + buf * (256 * 32);
    const u16* cB = Bs + buf * (128 * 32);
    s16x8 bfr[4];
#pragma unroll
    for (int j = 0; j < 4; j++)
      bfr[j] = *(const s16x8*)&cB[(wn + j * 16 + fr) * 32 + fo];
#pragma unroll
    for (int i = 0; i < 8; i++) {
      const s16x8 af = *(const s16x8*)&cA[(wm + i * 16 + fr) * 32 + fo];
#pragma unroll
      for (int j = 0; j < 4; j++)
        acc[i][j] = __builtin_amdgcn_mfma_f32_16x16x32_bf16(af, bfr[j], acc[i][j], 0, 0, 0);
    }
  };

  stage(0); stage(1);  // t0,t1 in flight (12 loads)
#pragma unroll 1
  for (int it = 0; it < 10; it++) {  // t = 3*it + {0,1,2}, t in [0,30)
    CHEB_WAIT(6); stage(2); compute(0);
    CHEB_WAIT(6); stage(0); compute(1);
    CHEB_WAIT(6); stage(1); compute(2);
  }
  CHEB_WAIT(6); compute(0);  // t=30
  CHEB_WAIT(0); compute(1);  // t=31
}

// gconv GEMM: C = Acat[4096x1024] @ X[1024 x 4224cols], outputs split by mat:
//   mt>>2: 0->X1 (S0*X), 1->X2 (T0*X), 2->X3 (S1*X), 3->X4 (T1*X); Xo[col][node].
__global__ __launch_bounds__(256, 2) void gconv_gemm(
    const u16* __restrict__ Acat, const u16* __restrict__ Bx,
    u16* __restrict__ X1, u16* __restrict__ X2,
    u16* __restrict__ X3, u16* __restrict__ X4) {
  __shared__ u16 As[3][256 * 32];
  __shared__ u16 Bs[3][128 * 32];
  const int t = threadIdx.x;
  const int lane = t & 63;
  const int w = t >> 6;

  // XCD swizzle (528 = 8*66): each XCD owns 2 m-tiles x all 33 n-tiles.
  const int lid = blockIdx.x;
  const int work = (lid & 7) * 66 + (lid >> 3);
  const int mt = work / 33;   // 0..15 (256-row A panel)
  const int nt = work % 33;   // col tile (128 cols)

  const int rl = lane >> 2;
  const int swz = ((lane & 3) ^ ((lane >> 3) & 3)) * 8;
  const u16* pA = Acat + (size_t)(mt * 256 + w * 64 + rl) * NN + swz;
  const u16* pB = Bx + (size_t)(nt * 128 + w * 32 + rl) * NN + swz;

  f32x4 acc[8][4];
#pragma unroll
  for (int i = 0; i < 8; i++)
#pragma unroll
    for (int j = 0; j < 4; j++) acc[i][j] = f32x4{0.f, 0.f, 0.f, 0.f};

  gemm256_pipe(pA, pB, &As[0][0], &Bs[0][0], w, lane, acc);

  const int md = mt >> 2;
  u16* Xo = md == 0 ? X1 : md == 1 ? X2 : md == 2 ? X3 : X4;
  const int m0 = (mt & 3) * 256;
  const int n0 = nt * 128;
  const int wm = (w >> 1) * 128;
  const int wn = (w & 1) * 64;
  const int fr = lane & 15;
  const int nr0 = (lane >> 4) << 2;
  // C/D layout: col = lane&15, row = (lane>>4)*4 + reg
#pragma unroll
  for (int i = 0; i < 8; i++) {
    const int node = m0 + wm + i * 16 + nr0;
#pragma unroll
    for (int j = 0; j < 4; j++) {
      const int colg = n0 + wn + j * 16 + fr;
      f32x4 c = acc[i][j];
      u16x4 o;
      o.x = f2bf(c.x); o.y = f2bf(c.y); o.z = f2bf(c.z); o.w = f2bf(c.w);
      *(u16x4*)&Xo[(size_t)colg * NN + node] = o;
    }
  }
}

// T_z = 2*S_z^2 - I into Acat T-rows. C[m][n] = ST_z[m] . S_z[n] = S^2[n][m];
// writes Acat[Tbase+n][m] = 2*C - (m==n) (row-major T, coalesced).
__global__ __launch_bounds__(256, 2) void sq_gemm(
    const u16* __restrict__ ST0, const u16* __restrict__ ST1, u16* Acat) {
  __shared__ u16 As[3][256 * 32];
  __shared__ u16 Bs[3][128 * 32];
  const int t = threadIdx.x;
  const int lane = t & 63;
  const int w = t >> 6;

  const int lid = blockIdx.x;   // 64 blocks: z x 4 m-tiles(256) x 8 n-tiles(128)
  const int z = lid >> 5;
  const int rr = lid & 31;
  const int mtile = rr >> 3, ntile = rr & 7;

  const u16* A = z ? ST1 : ST0;
  const u16* B = Acat + (size_t)(z * 2048) * NN;  // S_z rows of Acat

  const int rl = lane >> 2;
  const int swz = ((lane & 3) ^ ((lane >> 3) & 3)) * 8;
  const u16* pA = A + (size_t)(mtile * 256 + w * 64 + rl) * NN + swz;
  const u16* pB = B + (size_t)(ntile * 128 + w * 32 + rl) * NN + swz;

  f32x4 acc[8][4];
#pragma unroll
  for (int i = 0; i < 8; i++)
#pragma unroll
    for (int j = 0; j < 4; j++) acc[i][j] = f32x4{0.f, 0.f, 0.f, 0.f};

  gemm256_pipe(pA, pB, &As[0][0], &Bs[0][0], w, lane, acc);

  const size_t tbase = z ? 3072 : 1024;
  const int wm = (w >> 1) * 128;
  const int wn = (w & 1) * 64;
  const int fr = lane & 15;
  const int nr0 = (lane >> 4) << 2;
#pragma unroll
  for (int i = 0; i < 8; i++) {
    const int node = mtile * 256 + wm + i * 16 + nr0;  // m (= T col)
#pragma unroll
    for (int j = 0; j < 4; j++) {
      const int colg = ntile * 128 + wn + j * 16 + fr;  // n (= T row)
      f32x4 c = acc[i][j];
      u16x4 o;
      o.x = f2bf(2.f * c.x - (float)(node + 0 == colg));
      o.y = f2bf(2.f * c.y - (float)(node + 1 == colg));
      o.z = f2bf(2.f * c.z - (float)(node + 2 == colg));
      o.w = f2bf(2.f * c.w - (float)(node + 3 == colg));
      *(u16x4*)&Acat[(tbase + (size_t)colg) * NN + node] = o;
    }
  }
}

// ---------------- projections (MFMA) ----------------
// A-LDS [64 n][ASTRIDE kp]: staged via 4x4 register-transpose blocks
// (u16x4 global reads, u16x4 LDS writes); pad kp in [330,352) zeroed.

__device__ __forceinline__ void proj_stage(
    u16* A, const u16* __restrict__ X0, const u16* __restrict__ X1,
    const u16* __restrict__ X2, const u16* __restrict__ X3,
    const u16* __restrict__ X4, int b, int n0, int t) {
  for (int idx = t; idx < 1408; idx += 256) {  // 88 kp4-groups x 16 n4-groups
    const int kp0 = (idx >> 4) * 4;
    const int n4 = (idx & 15) * 4;
    u16x4 v[4];
#pragma unroll
    for (int r = 0; r < 4; r++) {
      const int kp = kp0 + r;
      if (kp < 330) {
        const int m = kp / 66;
        const int f = kp - m * 66;
        const u16* Xm = m == 0 ? X0 : m == 1 ? X1 : m == 2 ? X2 : m == 3 ? X3 : X4;
        v[r] = *(const u16x4*)(Xm + (size_t)(f * 64 + b) * NN + n0 + n4);
      } else {
        v[r] = u16x4{0, 0, 0, 0};
      }
    }
#pragma unroll
    for (int c = 0; c < 4; c++) {
      u16x4 o;
      o.x = v[0][c]; o.y = v[1][c]; o.z = v[2][c]; o.w = v[3][c];
      *(u16x4*)&A[(n4 + c) * ASTRIDE + kp0] = o;
    }
  }
}

// gconv1 projection: [64n x 330] @ Wt1^T -> 128 outs; sigmoid; r*hx -> X0'^T; u -> uout.
__global__ __launch_bounds__(256) void proj1(
    const u16* __restrict__ X0, const u16* __restrict__ X1, const u16* __restrict__ X2,
    const u16* __restrict__ X3, const u16* __restrict__ X4,
    const u16* __restrict__ Wt, const float* __restrict__ bias,
    const float* __restrict__ hx, u16* __restrict__ X0p, float* __restrict__ uout) {
  __shared__ u16 A[64 * ASTRIDE];
  const int t = threadIdx.x;
  const int n0 = blockIdx.x * 64;
  const int b = blockIdx.y;
  proj_stage(A, X0, X1, X2, X3, X4, b, n0, t);
  __syncthreads();

  const int lane = t & 63;
  const int w = t >> 6;
  const int fr = lane & 15;
  const int q8 = (lane >> 4) * 8;
  const u16* arow = &A[(w * 16 + fr) * ASTRIDE + q8];

  f32x4 acc[8];
#pragma unroll
  for (int j = 0; j < 8; j++) acc[j] = f32x4{0.f, 0.f, 0.f, 0.f};

  for (int kc = 0; kc < KPAD; kc += 32) {
    const s16x8 af = *(const s16x8*)(arow + kc);  // ONE b128 per k-step
#pragma unroll
    for (int j = 0; j < 8; j++) {
      const s16x8 bf = *(const s16x8*)&Wt[(size_t)(j * 16 + fr) * KPAD + kc + q8];
      acc[j] = __builtin_amdgcn_mfma_f32_16x16x32_bf16(af, bf, acc[j], 0, 0, 0);
    }
  }

  // D layout: col(o within sub) = lane&15, row(n within sub) = (lane>>4)*4 + reg
  const int nl0 = (lane >> 4) * 4;
  const int n = n0 + w * 16 + nl0;  // + reg
#pragma unroll
  for (int j = 0; j < 8; j++) {
    const int o = j * 16 + fr;
    const float bs = bias[o];
    f32x4 v;
    v.x = 1.f / (1.f + __expf(-(acc[j].x + bs)));
    v.y = 1.f / (1.f + __expf(-(acc[j].y + bs)));
    v.z = 1.f / (1.f + __expf(-(acc[j].z + bs)));
    v.w = 1.f / (1.f + __expf(-(acc[j].w + bs)));
    if (o < 64) {  // r-part -> X0'^T row (2+o)*64+b, times hx
      const float* hxp = hx + ((size_t)b << 16) + (size_t)n * 64 + o;
      u16x4 s;
      s.x = f2bf(v.x * hxp[0 * 64]);
      s.y = f2bf(v.y * hxp[1 * 64]);
      s.z = f2bf(v.z * hxp[2 * 64]);
      s.w = f2bf(v.w * hxp[3 * 64]);
      *(u16x4*)&X0p[(size_t)((2 + o) * 64 + b) * NN + n] = s;
    } else {  // u-part -> uout (d_out scratch)
      float* up = uout + (((size_t)b << 10) + n) * 64 + (o - 64);
      up[0 * 64] = v.x; up[1 * 64] = v.y; up[2 * 64] = v.z; up[3 * 64] = v.w;
    }
  }
}

// gconv2 projection: tanh + GRU blend. uin aliases out (same layout) - no restrict.
__global__ __launch_bounds__(256) void proj2(
    const u16* __restrict__ X0, const u16* __restrict__ X1, const u16* __restrict__ X2,
    const u16* __restrict__ X3, const u16* __restrict__ X4,
    const u16* __restrict__ Wt, const float* __restrict__ bias,
    const float* __restrict__ hx, const float* uin, float* out) {
  __shared__ u16 A[64 * ASTRIDE];
  const int t = threadIdx.x;
  const int n0 = blockIdx.x * 64;
  const int b = blockIdx.y;
  proj_stage(A, X0, X1, X2, X3, X4, b, n0, t);
  __syncthreads();

  const int lane = t & 63;
  const int w = t >> 6;
  const int fr = lane & 15;
  const int q8 = (lane >> 4) * 8;
  const u16* arow = &A[(w * 16 + fr) * ASTRIDE + q8];

  f32x4 acc[4];
#pragma unroll
  for (int j = 0; j < 4; j++) acc[j] = f32x4{0.f, 0.f, 0.f, 0.f};

  for (int kc = 0; kc < KPAD; kc += 32) {
    const s16x8 af = *(const s16x8*)(arow + kc);
#pragma unroll
    for (int j = 0; j < 4; j++) {
      const s16x8 bf = *(const s16x8*)&Wt[(size_t)(j * 16 + fr) * KPAD + kc + q8];
      acc[j] = __builtin_amdgcn_mfma_f32_16x16x32_bf16(af, bf, acc[j], 0, 0, 0);
    }
  }

  const int nl0 = (lane >> 4) * 4;
  const int n = n0 + w * 16 + nl0;  // + reg
#pragma unroll
  for (int j = 0; j < 4; j++) {
    const int o = j * 16 + fr;
    const float bs = bias[o];
    const size_t base = (((size_t)b << 10) + n) * 64 + o;  // + reg*64
    float c0 = tanhf(acc[j].x + bs);
    float c1 = tanhf(acc[j].y + bs);
    float c2 = tanhf(acc[j].z + bs);
    float c3 = tanhf(acc[j].w + bs);
    float u0 = uin[base + 0 * 64], u1 = uin[base + 1 * 64];
    float u2 = uin[base + 2 * 64], u3 = uin[base + 3 * 64];
    float h0 = hx[base + 0 * 64], h1 = hx[base + 1 * 64];
    float h2 = hx[base + 2 * 64], h3 = hx[base + 3 * 64];
    out[base + 0 * 64] = u0 * h0 + (1.f - u0) * c0;
    out[base + 1 * 64] = u1 * h1 + (1.f - u1) * c1;
    out[base + 2 * 64] = u2 * h2 + (1.f - u2) * c2;
    out[base + 3 * 64] = u3 * h3 + (1.f - u3) * c3;
  }
}

// ---------------- launch ----------------

extern "C" void kernel_launch(void* const* d_in, const int* in_sizes, int n_in,
                              void* d_out, int out_size, void* d_ws, size_t ws_size,
                              hipStream_t stream) {
  (void)in_sizes; (void)n_in; (void)out_size; (void)ws_size;
  const float* inp = (const float*)d_in[0];
  const float* hx  = (const float*)d_in[1];
  const float* s0  = (const float*)d_in[2];
  const float* s1  = (const float*)d_in[3];
  const float* Wo  = (const float*)d_in[4];
  const float* bo  = (const float*)d_in[5];
  const float* Wu  = (const float*)d_in[6];
  const float* bu  = (const float*)d_in[7];
  float* out = (float*)d_out;

  char* p = (char*)d_ws;
  u16* Acat = (u16*)p; p += (size_t)4096 * NN * 2;  // [S0;T0;S1;T1]
  u16* ST0  = (u16*)p; p += (size_t)NN * NN * 2;
  u16* ST1  = (u16*)p; p += (size_t)NN * NN * 2;
  const size_t xbytes = (size_t)NCOLS * NN * 2;
  u16* X0T = (u16*)p; p += xbytes;
  u16* X1T = (u16*)p; p += xbytes;
  u16* X2T = (u16*)p; p += xbytes;
  u16* X3T = (u16*)p; p += xbytes;
  u16* X4T = (u16*)p; p += xbytes;
  u16* X0P = (u16*)p; p += xbytes;
  u16* Wt1 = (u16*)p; p += (size_t)128 * KPAD * 2;
  u16* Wt2 = (u16*)p; p += (size_t)64 * KPAD * 2;
  // total ws use: 8 + 4 MB + 6*8.25 MB + ~132 KB

  pack_supports<<<dim3(256, 2), dim3(256), 0, stream>>>(s0, s1, Acat, ST0, ST1);
  sq_gemm<<<dim3(64), dim3(256), 0, stream>>>(ST0, ST1, Acat);
  pack_w<<<dim3(6, 128), dim3(64), 0, stream>>>(Wo, Wt1, 128);
  pack_w<<<dim3(6, 64), dim3(64), 0, stream>>>(Wu, Wt2, 64);
  pack_x0_inputs<<<dim3(64), dim3(256), 0, stream>>>(inp, X0T, X0P);
  pack_x0_hx<<<dim3(16, 64), dim3(256), 0, stream>>>(hx, X0T);
  // gconv1: X1=S0 X0, X2=T0 X0, X3=S1 X0, X4=T1 X0  (one launch)
  gconv_gemm<<<dim3(528), dim3(256), 0, stream>>>(Acat, X0T, X1T, X2T, X3T, X4T);
  proj1<<<dim3(16, 64), dim3(256), 0, stream>>>(X0T, X1T, X2T, X3T, X4T, Wt1, bo, hx, X0P, out);
  // gconv2 on X0'
  gconv_gemm<<<dim3(528), dim3(256), 0, stream>>>(Acat, X0P, X1T, X2T, X3T, X4T);
  proj2<<<dim3(16, 64), dim3(256), 0, stream>>>(X0P, X1T, X2T, X3T, X4T, Wt2, bu, hx, out, out);
}

// Round 5
// 289.100 us; speedup vs baseline: 1.1724x; 1.1724x over previous
//
#include <hip/hip_runtime.h>

// DCGRU cell, MI355X.  (Revert to R2 best-measured base + coalesced W-frags.)
//   Diffusion intermediates TRANSPOSED: XT[col = f*64+b][node n] in bf16.
//   cheb_gemm: 128x128 tile, BK=32, TRIPLE-buffered LDS, raw s_barrier +
//     counted "s_waitcnt vmcnt(4)" (never 0 in main loop). XOR swizzle via
//     pre-swizzled GLOBAL source (global_load_lds writes linearly).
//     XCD-bijective block swizzle (nwg=528, 528%8==0).
//   proj1/proj2: A staged in LDS as [n][kp] row stride 360 (720B: 5n mod 8
//     bijective -> conflict-free ds_read_b128 A-frags, ONE per 32-k step).
//     B-frags from global WF in FRAGMENT ORDER: WF[(c*nj+j)*64+lane][8]
//     -> each wave's (j,kc) B-load is one coalesced 1KB stream (was 16B x
//     16 lanes at 704B stride = 4x line over-fetch + L1 thrash).
//   d_out doubles as u-buffer.

typedef unsigned short u16;
typedef unsigned int u32;
typedef short s16x8 __attribute__((ext_vector_type(8)));
typedef float f32x4 __attribute__((ext_vector_type(4)));
typedef u16 u16x4 __attribute__((ext_vector_type(4)));

#define NN 1024
#define NB 64
#define NF 66
#define NCOLS 4224  // NF*NB
#define KPAD 352    // 330 padded to 11*32
#define ASTRIDE 360 // proj A-LDS row stride in u16 (720B, 5n%8 bijection)

__device__ __forceinline__ u16 f2bf(float f) {
  u32 u = __builtin_bit_cast(u32, f);
  u = (u + 0x7fffu + ((u >> 16) & 1u)) >> 16;  // RNE
  return (u16)u;
}
__device__ __forceinline__ float bf2f(u16 h) {
  u32 u = ((u32)h) << 16;
  return __builtin_bit_cast(float, u);
}

__device__ __forceinline__ void gload16(const void* g, void* l) {
  __builtin_amdgcn_global_load_lds(
      (const __attribute__((address_space(1))) u32*)g,
      (__attribute__((address_space(3))) u32*)l, 16, 0, 0);
}

// counted-vmcnt barrier: own oldest loads landed -> barrier -> fence reads
#define CHEB_WAIT(N)                                      \
  do {                                                    \
    asm volatile("s_waitcnt vmcnt(" #N ")" ::: "memory"); \
    __builtin_amdgcn_s_barrier();                         \
    asm volatile("" ::: "memory");                        \
  } while (0)

// ---------------- pack kernels ----------------

__global__ __launch_bounds__(256) void pack_supports(
    const float* __restrict__ s0, const float* __restrict__ s1,
    u16* __restrict__ d0, u16* __restrict__ d1) {
  int i = (blockIdx.x * 256 + threadIdx.x) * 4;
  f32x4 a = *(const f32x4*)(s0 + i);
  f32x4 b = *(const f32x4*)(s1 + i);
  u16x4 oa, ob;
  oa.x = f2bf(a.x); oa.y = f2bf(a.y); oa.z = f2bf(a.z); oa.w = f2bf(a.w);
  ob.x = f2bf(b.x); ob.y = f2bf(b.y); ob.z = f2bf(b.z); ob.w = f2bf(b.w);
  *(u16x4*)(d0 + i) = oa;
  *(u16x4*)(d1 + i) = ob;
}

// WF[(c*nj+j)*64 + lane][e]: fragment-ordered W so proj B-frag reads coalesce.
// kp = c*32 + (lane>>4)*8 + e, o = j*16 + (lane&15); zero-pad kp in [330,352).
__global__ __launch_bounds__(64) void pack_wf(
    const float* __restrict__ W, u16* __restrict__ WF, int ldo, int nj) {
  const int c = blockIdx.x;   // 0..10
  const int j = blockIdx.y;   // 0..nj-1
  const int lane = threadIdx.x;
  const int o = j * 16 + (lane & 15);
  const int kpb = c * 32 + (lane >> 4) * 8;
  u16 vals[8];
#pragma unroll
  for (int e = 0; e < 8; e++) {
    const int kp = kpb + e;
    float v = 0.f;
    if (kp < 330) {
      const int m = kp / 66;
      const int f = kp - m * 66;
      v = W[(f * 5 + m) * ldo + o];
    }
    vals[e] = f2bf(v);
  }
  u16* dst = WF + (((size_t)(c * nj + j) << 6) + lane) * 8;
#pragma unroll
  for (int e = 0; e < 8; e++) dst[e] = vals[e];
}

// rows f=0,1 of X0^T and X0'^T: X0T[f*64+b][n] = inputs[b][2n+f]
__global__ __launch_bounds__(256) void pack_x0_inputs(
    const float* __restrict__ inp, u16* __restrict__ x0t, u16* __restrict__ x0pt) {
  int b = blockIdx.x, t = threadIdx.x;
  int n4 = t * 4;
  const float* src = inp + b * 2048 + n4 * 2;
  f32x4 a = *(const f32x4*)src;
  f32x4 c = *(const f32x4*)(src + 4);
  u16x4 r0, r1;
  r0.x = f2bf(a.x); r0.y = f2bf(a.z); r0.z = f2bf(c.x); r0.w = f2bf(c.z);  // f=0
  r1.x = f2bf(a.y); r1.y = f2bf(a.w); r1.z = f2bf(c.y); r1.w = f2bf(c.w);  // f=1
  size_t o0 = (size_t)(b)*NN + n4;
  size_t o1 = (size_t)(64 + b) * NN + n4;
  *(u16x4*)(x0t + o0) = r0;  *(u16x4*)(x0t + o1) = r1;
  *(u16x4*)(x0pt + o0) = r0; *(u16x4*)(x0pt + o1) = r1;
}

// rows f>=2 of X0^T: X0T[(2+u)*64+b][n] = hx[b][n*64+u]  (64x64 LDS transpose tiles)
__global__ __launch_bounds__(256) void pack_x0_hx(
    const float* __restrict__ hx, u16* __restrict__ x0t) {
  __shared__ float tile[64][65];
  int n0 = blockIdx.x * 64, b = blockIdx.y, t = threadIdx.x;
  int u4 = (t & 15) * 4, r0 = t >> 4;
#pragma unroll
  for (int p = 0; p < 4; p++) {
    int row = p * 16 + r0;
    f32x4 v = *(const f32x4*)(hx + ((size_t)b << 16) + (size_t)(n0 + row) * 64 + u4);
    tile[row][u4] = v.x; tile[row][u4 + 1] = v.y;
    tile[row][u4 + 2] = v.z; tile[row][u4 + 3] = v.w;
  }
  __syncthreads();
  int n4 = (t & 15) * 4, uu0 = t >> 4;
#pragma unroll
  for (int p = 0; p < 4; p++) {
    int u = p * 16 + uu0;
    u16x4 o;
    o.x = f2bf(tile[n4][u]);     o.y = f2bf(tile[n4 + 1][u]);
    o.z = f2bf(tile[n4 + 2][u]); o.w = f2bf(tile[n4 + 3][u]);
    *(u16x4*)&x0t[(size_t)((2 + u) * 64 + b) * NN + n0 + n4] = o;
  }
}

// ---------------- Chebyshev GEMM ----------------
// C[node][col] = S_z[node][:] . XT_z[col][:],  write Xo_z[col][node] (bf16),
// optional fused epilogue: 2*C - Xprev.
// LDS buffer: [128 rows][4 chunks of 16B]; logical chunk c of row r at
// physical chunk c^((r>>1)&3) (staged via pre-swizzled global source addr).

__global__ __launch_bounds__(256, 3) void cheb_gemm(
    const u16* __restrict__ S0, const u16* __restrict__ S1,
    const u16* __restrict__ Xi0, const u16* __restrict__ Xi1,
    u16* __restrict__ Xo0, u16* __restrict__ Xo1,
    const u16* __restrict__ Xprev, int use_prev) {
  __shared__ u16 As[3][128 * 32];
  __shared__ u16 Bs[3][128 * 32];
  const int t = threadIdx.x;
  const int lane = t & 63;
  const int w = t >> 6;

  // XCD-bijective swizzle (nwg=528, r=0): each XCD gets 66 consecutive work
  // ids = ~8 col-tiles of one support x all 8 node-tiles -> S_z + Xi panel L2-hot.
  const int lid = blockIdx.x;
  const int work = (lid & 7) * 66 + (lid >> 3);
  const int y = work & 7;     // node tile
  const int tt = work >> 3;   // 0..65
  const int x = tt % 33;      // col tile
  const int z = tt / 33;      // support
  const int n0 = x * 128;
  const int m0 = y * 128;
  const u16* S = z ? S1 : S0;
  const u16* Xi = z ? Xi1 : Xi0;
  u16* Xo = z ? Xo1 : Xo0;

  // staging: wave w covers rows [w*32, w*32+32), 2 gloads x 16 rows per matrix.
  const int swz = ((lane & 3) ^ ((lane >> 3) & 3)) * 8;  // u16 offset in row
  const int rl = lane >> 2;
  const u16* pA0 = S + (size_t)(m0 + w * 32 + rl) * NN + swz;
  const u16* pA1 = pA0 + (size_t)16 * NN;
  const u16* pB0 = Xi + (size_t)(n0 + w * 32 + rl) * NN + swz;
  const u16* pB1 = pB0 + (size_t)16 * NN;
  const int db0 = (w * 32) * 32;        // LDS u16 offset, wave-uniform
  const int db1 = (w * 32 + 16) * 32;

  const int wm = (w >> 1) * 64;
  const int wn = (w & 1) * 64;
  const int fr = lane & 15;
  const int q = lane >> 4;
  // frag read: row = base+fr, logical chunk q -> physical q^((fr>>1)&3)
  const int fo = (q ^ ((fr >> 1) & 3)) * 8;

  f32x4 acc[4][4];
#pragma unroll
  for (int i = 0; i < 4; i++)
#pragma unroll
    for (int j = 0; j < 4; j++) acc[i][j] = f32x4{0.f, 0.f, 0.f, 0.f};

  auto stage = [&](u16* dA, u16* dB) {
    gload16(pA0, dA + db0);
    gload16(pA1, dA + db1);
    gload16(pB0, dB + db0);
    gload16(pB1, dB + db1);
    pA0 += 32; pA1 += 32; pB0 += 32; pB1 += 32;
  };
  auto compute = [&](const u16* cA, const u16* cB) {
    s16x8 af[4], bfr[4];
#pragma unroll
    for (int i = 0; i < 4; i++)
      af[i] = *(const s16x8*)&cA[(wm + i * 16 + fr) * 32 + fo];
#pragma unroll
    for (int j = 0; j < 4; j++)
      bfr[j] = *(const s16x8*)&cB[(wn + j * 16 + fr) * 32 + fo];
#pragma unroll
    for (int i = 0; i < 4; i++)
#pragma unroll
      for (int j = 0; j < 4; j++)
        acc[i][j] = __builtin_amdgcn_mfma_f32_16x16x32_bf16(af[i], bfr[j], acc[i][j], 0, 0, 0);
  };

  u16* a0 = &As[0][0]; u16* a1 = &As[1][0]; u16* a2 = &As[2][0];
  u16* b0 = &Bs[0][0]; u16* b1 = &Bs[1][0]; u16* b2 = &Bs[2][0];

  // pipeline: stage t=0,1; steady state keeps 8 loads in flight, waits only
  // for the 2-iteration-old tile (vmcnt(4)); vmcnt(0) only at the last step.
  stage(a0, b0);
  stage(a1, b1);
#pragma unroll 1
  for (int it = 0; it < 10; it++) {  // t = 3*it + {0,1,2}, t in [0,30)
    CHEB_WAIT(4); stage(a2, b2); compute(a0, b0);
    CHEB_WAIT(4); stage(a0, b0); compute(a1, b1);
    CHEB_WAIT(4); stage(a1, b1); compute(a2, b2);
  }
  CHEB_WAIT(4); compute(a0, b0);  // t=30
  CHEB_WAIT(0); compute(a1, b1);  // t=31

  // C/D layout: col = lane&15, row = (lane>>4)*4 + reg
  const int nr0 = (lane >> 4) << 2;
#pragma unroll
  for (int i = 0; i < 4; i++) {
    const int node = m0 + wm + i * 16 + nr0;
#pragma unroll
    for (int j = 0; j < 4; j++) {
      const int colg = n0 + wn + j * 16 + fr;
      size_t off = (size_t)colg * NN + node;
      f32x4 c = acc[i][j];
      if (use_prev) {
        u16x4 p = *(const u16x4*)&Xprev[off];
        c.x = 2.f * c.x - bf2f(p.x);
        c.y = 2.f * c.y - bf2f(p.y);
        c.z = 2.f * c.z - bf2f(p.z);
        c.w = 2.f * c.w - bf2f(p.w);
      }
      u16x4 o;
      o.x = f2bf(c.x); o.y = f2bf(c.y); o.z = f2bf(c.z); o.w = f2bf(c.w);
      *(u16x4*)&Xo[off] = o;
    }
  }
}

// ---------------- projections (MFMA) ----------------
// A-LDS [64 n][ASTRIDE kp]: staged via 4x4 register-transpose blocks
// (u16x4 global reads, u16x4 LDS writes); pad kp in [330,352) zeroed.

__device__ __forceinline__ void proj_stage(
    u16* A, const u16* __restrict__ X0, const u16* __restrict__ X1,
    const u16* __restrict__ X2, const u16* __restrict__ X3,
    const u16* __restrict__ X4, int b, int n0, int t) {
  for (int idx = t; idx < 1408; idx += 256) {  // 88 kp4-groups x 16 n4-groups
    const int kp0 = (idx >> 4) * 4;
    const int n4 = (idx & 15) * 4;
    u16x4 v[4];
#pragma unroll
    for (int r = 0; r < 4; r++) {
      const int kp = kp0 + r;
      if (kp < 330) {
        const int m = kp / 66;
        const int f = kp - m * 66;
        const u16* Xm = m == 0 ? X0 : m == 1 ? X1 : m == 2 ? X2 : m == 3 ? X3 : X4;
        v[r] = *(const u16x4*)(Xm + (size_t)(f * 64 + b) * NN + n0 + n4);
      } else {
        v[r] = u16x4{0, 0, 0, 0};
      }
    }
#pragma unroll
    for (int c = 0; c < 4; c++) {
      u16x4 o;
      o.x = v[0][c]; o.y = v[1][c]; o.z = v[2][c]; o.w = v[3][c];
      *(u16x4*)&A[(n4 + c) * ASTRIDE + kp0] = o;
    }
  }
}

// gconv1 projection: [64n x 330] @ W1 -> 128 outs; sigmoid; r*hx -> X0'^T; u -> uout.
__global__ __launch_bounds__(256) void proj1(
    const u16* __restrict__ X0, const u16* __restrict__ X1, const u16* __restrict__ X2,
    const u16* __restrict__ X3, const u16* __restrict__ X4,
    const u16* __restrict__ WF, const float* __restrict__ bias,
    const float* __restrict__ hx, u16* __restrict__ X0p, float* __restrict__ uout) {
  __shared__ u16 A[64 * ASTRIDE];
  const int t = threadIdx.x;
  const int n0 = blockIdx.x * 64;
  const int b = blockIdx.y;
  proj_stage(A, X0, X1, X2, X3, X4, b, n0, t);
  __syncthreads();

  const int lane = t & 63;
  const int w = t >> 6;
  const int fr = lane & 15;
  const int q8 = (lane >> 4) * 8;
  const u16* arow = &A[(w * 16 + fr) * ASTRIDE + q8];
  const u16* wfl = WF + (size_t)lane * 8;  // + (c*8+j)*512

  f32x4 acc[8];
#pragma unroll
  for (int j = 0; j < 8; j++) acc[j] = f32x4{0.f, 0.f, 0.f, 0.f};

  for (int c = 0; c < 11; c++) {
    const s16x8 af = *(const s16x8*)(arow + c * 32);  // ONE b128 per k-step
#pragma unroll
    for (int j = 0; j < 8; j++) {
      const s16x8 bf = *(const s16x8*)(wfl + ((c * 8 + j) << 9));  // coalesced 1KB/wave
      acc[j] = __builtin_amdgcn_mfma_f32_16x16x32_bf16(af, bf, acc[j], 0, 0, 0);
    }
  }

  // D layout: col(o within sub) = lane&15, row(n within sub) = (lane>>4)*4 + reg
  const int nl0 = (lane >> 4) * 4;
  const int n = n0 + w * 16 + nl0;  // + reg
#pragma unroll
  for (int j = 0; j < 8; j++) {
    const int o = j * 16 + fr;
    const float bs = bias[o];
    f32x4 v;
    v.x = 1.f / (1.f + __expf(-(acc[j].x + bs)));
    v.y = 1.f / (1.f + __expf(-(acc[j].y + bs)));
    v.z = 1.f / (1.f + __expf(-(acc[j].z + bs)));
    v.w = 1.f / (1.f + __expf(-(acc[j].w + bs)));
    if (o < 64) {  // r-part -> X0'^T row (2+o)*64+b, times hx
      const float* hxp = hx + ((size_t)b << 16) + (size_t)n * 64 + o;
      u16x4 s;
      s.x = f2bf(v.x * hxp[0 * 64]);
      s.y = f2bf(v.y * hxp[1 * 64]);
      s.z = f2bf(v.z * hxp[2 * 64]);
      s.w = f2bf(v.w * hxp[3 * 64]);
      *(u16x4*)&X0p[(size_t)((2 + o) * 64 + b) * NN + n] = s;
    } else {  // u-part -> uout (d_out scratch)
      float* up = uout + (((size_t)b << 10) + n) * 64 + (o - 64);
      up[0 * 64] = v.x; up[1 * 64] = v.y; up[2 * 64] = v.z; up[3 * 64] = v.w;
    }
  }
}

// gconv2 projection: tanh + GRU blend. uin aliases out (same layout) - no restrict.
__global__ __launch_bounds__(256) void proj2(
    const u16* __restrict__ X0, const u16* __restrict__ X1, const u16* __restrict__ X2,
    const u16* __restrict__ X3, const u16* __restrict__ X4,
    const u16* __restrict__ WF, const float* __restrict__ bias,
    const float* __restrict__ hx, const float* uin, float* out) {
  __shared__ u16 A[64 * ASTRIDE];
  const int t = threadIdx.x;
  const int n0 = blockIdx.x * 64;
  const int b = blockIdx.y;
  proj_stage(A, X0, X1, X2, X3, X4, b, n0, t);
  __syncthreads();

  const int lane = t & 63;
  const int w = t >> 6;
  const int fr = lane & 15;
  const int q8 = (lane >> 4) * 8;
  const u16* arow = &A[(w * 16 + fr) * ASTRIDE + q8];
  const u16* wfl = WF + (size_t)lane * 8;  // + (c*4+j)*512

  f32x4 acc[4];
#pragma unroll
  for (int j = 0; j < 4; j++) acc[j] = f32x4{0.f, 0.f, 0.f, 0.f};

  for (int c = 0; c < 11; c++) {
    const s16x8 af = *(const s16x8*)(arow + c * 32);
#pragma unroll
    for (int j = 0; j < 4; j++) {
      const s16x8 bf = *(const s16x8*)(wfl + ((c * 4 + j) << 9));  // coalesced
      acc[j] = __builtin_amdgcn_mfma_f32_16x16x32_bf16(af, bf, acc[j], 0, 0, 0);
    }
  }

  const int nl0 = (lane >> 4) * 4;
  const int n = n0 + w * 16 + nl0;  // + reg
#pragma unroll
  for (int j = 0; j < 4; j++) {
    const int o = j * 16 + fr;
    const float bs = bias[o];
    const size_t base = (((size_t)b << 10) + n) * 64 + o;  // + reg*64
    float c0 = tanhf(acc[j].x + bs);
    float c1 = tanhf(acc[j].y + bs);
    float c2 = tanhf(acc[j].z + bs);
    float c3 = tanhf(acc[j].w + bs);
    float u0 = uin[base + 0 * 64], u1 = uin[base + 1 * 64];
    float u2 = uin[base + 2 * 64], u3 = uin[base + 3 * 64];
    float h0 = hx[base + 0 * 64], h1 = hx[base + 1 * 64];
    float h2 = hx[base + 2 * 64], h3 = hx[base + 3 * 64];
    out[base + 0 * 64] = u0 * h0 + (1.f - u0) * c0;
    out[base + 1 * 64] = u1 * h1 + (1.f - u1) * c1;
    out[base + 2 * 64] = u2 * h2 + (1.f - u2) * c2;
    out[base + 3 * 64] = u3 * h3 + (1.f - u3) * c3;
  }
}

// ---------------- launch ----------------

extern "C" void kernel_launch(void* const* d_in, const int* in_sizes, int n_in,
                              void* d_out, int out_size, void* d_ws, size_t ws_size,
                              hipStream_t stream) {
  (void)in_sizes; (void)n_in; (void)out_size; (void)ws_size;
  const float* inp = (const float*)d_in[0];
  const float* hx  = (const float*)d_in[1];
  const float* s0  = (const float*)d_in[2];
  const float* s1  = (const float*)d_in[3];
  const float* Wo  = (const float*)d_in[4];
  const float* bo  = (const float*)d_in[5];
  const float* Wu  = (const float*)d_in[6];
  const float* bu  = (const float*)d_in[7];
  float* out = (float*)d_out;

  char* p = (char*)d_ws;
  u16* Sb0 = (u16*)p; p += (size_t)NN * NN * 2;
  u16* Sb1 = (u16*)p; p += (size_t)NN * NN * 2;
  const size_t xbytes = (size_t)NCOLS * NN * 2;
  u16* X0T = (u16*)p; p += xbytes;
  u16* X1T = (u16*)p; p += xbytes;
  u16* X2T = (u16*)p; p += xbytes;
  u16* X3T = (u16*)p; p += xbytes;
  u16* X4T = (u16*)p; p += xbytes;
  u16* X0P = (u16*)p; p += xbytes;
  u16* WF1 = (u16*)p; p += (size_t)11 * 8 * 512 * 2;  // 90112 B
  u16* WF2 = (u16*)p; p += (size_t)11 * 4 * 512 * 2;  // 45056 B
  // total ws use: 4 MB + 6*8.25 MB + ~132 KB

  pack_supports<<<dim3(1024), dim3(256), 0, stream>>>(s0, s1, Sb0, Sb1);
  pack_wf<<<dim3(11, 8), dim3(64), 0, stream>>>(Wo, WF1, 128, 8);
  pack_wf<<<dim3(11, 4), dim3(64), 0, stream>>>(Wu, WF2, 64, 4);
  pack_x0_inputs<<<dim3(64), dim3(256), 0, stream>>>(inp, X0T, X0P);
  pack_x0_hx<<<dim3(16, 64), dim3(256), 0, stream>>>(hx, X0T);
  // gconv1 Chebyshev: X1=S0 X0, X3=S1 X0 ; X2=2 S0 X1 - X0, X4=2 S1 X3 - X0
  cheb_gemm<<<dim3(528), dim3(256), 0, stream>>>(Sb0, Sb1, X0T, X0T, X1T, X3T,
                                                 (const u16*)nullptr, 0);
  cheb_gemm<<<dim3(528), dim3(256), 0, stream>>>(Sb0, Sb1, X1T, X3T, X2T, X4T, X0T, 1);
  proj1<<<dim3(16, 64), dim3(256), 0, stream>>>(X0T, X1T, X2T, X3T, X4T, WF1, bo, hx, X0P, out);
  // gconv2 Chebyshev on X0' (reuse X1..X4 buffers)
  cheb_gemm<<<dim3(528), dim3(256), 0, stream>>>(Sb0, Sb1, X0P, X0P, X1T, X3T,
                                                 (const u16*)nullptr, 0);
  cheb_gemm<<<dim3(528), dim3(256), 0, stream>>>(Sb0, Sb1, X1T, X3T, X2T, X4T, X0P, 1);
  proj2<<<dim3(16, 64), dim3(256), 0, stream>>>(X0P, X1T, X2T, X3T, X4T, WF2, bu, hx, out, out);
}